// Round 12
// baseline (217.344 us; speedup 1.0000x reference)
//
#include <hip/hip_runtime.h>
#include <cstddef>

typedef __attribute__((ext_vector_type(8))) short short8;
typedef __attribute__((ext_vector_type(4))) float f4;
typedef __attribute__((ext_vector_type(4))) unsigned int u4;
typedef __attribute__((ext_vector_type(2))) unsigned int u2;

__device__ __forceinline__ unsigned int f2bf(float f){
  unsigned int u = __float_as_uint(f);
  u += 0x7fffu + ((u >> 16) & 1u);   // RNE to bf16
  return u >> 16;
}
__device__ __forceinline__ float bflo(unsigned int w){ return __uint_as_float((w & 0xFFFFu) << 16); }
__device__ __forceinline__ float bfhi(unsigned int w){ return __uint_as_float(w & 0xFFFF0000u); }
__device__ __forceinline__ float fsign(float x){ return (x > 0.f) ? 1.f : ((x < 0.f) ? -1.f : 0.f); }
__device__ __forceinline__ float hclip(float x){ return fminf(1.f, fmaxf(-1.f, x)); }

#define SB0 __builtin_amdgcn_sched_barrier(0)

// lgkm-only barrier (vmem loads stay in flight)
#define BARRIER() do { \
    SB0; \
    asm volatile("s_waitcnt lgkmcnt(0)" ::: "memory"); \
    __builtin_amdgcn_s_barrier(); \
    asm volatile("" ::: "memory"); \
    SB0; \
  } while(0)

// counted-vmcnt barrier: drain all but N newest vmem ops, then workgroup barrier
#define VBAR(N) do { \
    SB0; \
    asm volatile("s_waitcnt vmcnt(" #N ") lgkmcnt(0)" ::: "memory"); \
    __builtin_amdgcn_s_barrier(); \
    asm volatile("" ::: "memory"); \
    SB0; \
  } while(0)

// global -> LDS direct DMA, 16B per lane
#define GL16(gp, lp) __builtin_amdgcn_global_load_lds( \
    (const __attribute__((address_space(1))) void*)(gp), \
    (__attribute__((address_space(3))) void*)(lp), 16, 0, 0)

// ---------------- prep: sign(W1)+sign(W2) fp32 -> bf16 {+1,-1,0}, one dispatch ----------------
__global__ void prep_sign_k(const float* __restrict__ W1, unsigned short* __restrict__ w1s,
                            const float* __restrict__ W2, unsigned short* __restrict__ w2s){
  int i = (blockIdx.x * blockDim.x + threadIdx.x) * 8;
  const float* w; unsigned short* o; int off;
  if (i < 1048576){ w = W1; o = w1s; off = i; }
  else            { w = W2; o = w2s; off = i - 1048576; if (off >= 32768) return; }
  f4 a = *(const f4*)(w + off);
  f4 b = *(const f4*)(w + off + 4);
  unsigned short s[8];
  #pragma unroll
  for (int j = 0; j < 4; j++) s[j]   = (a[j] > 0.f) ? 0x3F80u : ((a[j] < 0.f) ? 0xBF80u : 0u);
  #pragma unroll
  for (int j = 0; j < 4; j++) s[4+j] = (b[j] > 0.f) ? 0x3F80u : ((b[j] < 0.f) ? 0xBF80u : 0u);
  u4 v;
  v.x = (unsigned)s[0] | ((unsigned)s[1] << 16);
  v.y = (unsigned)s[2] | ((unsigned)s[3] << 16);
  v.z = (unsigned)s[4] | ((unsigned)s[5] << 16);
  v.w = (unsigned)s[6] | ((unsigned)s[7] << 16);
  *(u4*)(o + off) = v;
}

// ---------------- GEMM1: h1(bf16) = x @ signW1^T + sign(b1), fused transposed col-stats ---------
// BM=64, BN=256, BK=128, 32 K-steps. 512 thr = 8 waves, wave tile 32x64.
// A: GL16 -> 4 x 32KB LDS bufs, depth-3 issue; fp32->bf16 convert at frag read;
//    swizzle (m&7)<<4 at 16B granule -> 2-way (free) on b128 reads.
// B: registers, double-set (B(k+1) issued at step k, BEFORE A(k+3)); per step exactly
//    16 B-loads + 4 A-GL16s -> VBAR(24) waits only A(k+1); A slack = 2 steps (~6400cy);
//    in-flight A ~64-96 KB/CU (Little's-law target for loaded HBM latency).
__global__ __launch_bounds__(512, 2) void gemm1_k(
    const float* __restrict__ x, const unsigned short* __restrict__ w1s,
    const float* __restrict__ b1, unsigned short* __restrict__ h1,
    float* __restrict__ part1s, float* __restrict__ part1q)
{
  __shared__ __align__(16) char lds[131072];   // 4 x 32KB A buffers
  const int tid  = threadIdx.x;
  const int lane = tid & 63;
  const int wid  = tid >> 6;
  const int wm   = wid >> 2;          // 0..1 -> rows wm*32..+31
  const int wn   = wid & 3;           // 0..3 -> cols wn*64..+63
  const int cl   = lane & 15;
  const int g    = lane >> 4;         // 0..3
  const int row0 = blockIdx.x * 64;

  // B direct-load bases (per fn): row n = wn*64 + fn*16 + cl, lane byte g*16
  const char* bb0 = (const char*)w1s + (size_t)(wn*64 +  0 + cl) * 8192 + g * 16;
  const char* bb1 = (const char*)w1s + (size_t)(wn*64 + 16 + cl) * 8192 + g * 16;
  const char* bb2 = (const char*)w1s + (size_t)(wn*64 + 32 + cl) * 8192 + g * 16;
  const char* bb3 = (const char*)w1s + (size_t)(wn*64 + 48 + cl) * 8192 + g * 16;

  f4 acc[2][4];
  const f4 z = {0.f, 0.f, 0.f, 0.f};
  #pragma unroll
  for (int i = 0; i < 2; i++)
    #pragma unroll
    for (int j = 0; j < 4; j++) acc[i][j] = z;

  // B double-set registers (named; fn,ks literal digits)
  short8 B0_00, B0_01, B0_02, B0_03, B0_10, B0_11, B0_12, B0_13;
  short8 B0_20, B0_21, B0_22, B0_23, B0_30, B0_31, B0_32, B0_33;
  short8 B1_00, B1_01, B1_02, B1_03, B1_10, B1_11, B1_12, B1_13;
  short8 B1_20, B1_21, B1_22, B1_23, B1_30, B1_31, B1_32, B1_33;

#define ISSUEB(S, K) do { \
    const size_t _ko = (size_t)(K) * 256; \
    B##S##_00 = *(const short8*)(bb0 + _ko +   0); \
    B##S##_01 = *(const short8*)(bb0 + _ko +  64); \
    B##S##_02 = *(const short8*)(bb0 + _ko + 128); \
    B##S##_03 = *(const short8*)(bb0 + _ko + 192); \
    B##S##_10 = *(const short8*)(bb1 + _ko +   0); \
    B##S##_11 = *(const short8*)(bb1 + _ko +  64); \
    B##S##_12 = *(const short8*)(bb1 + _ko + 128); \
    B##S##_13 = *(const short8*)(bb1 + _ko + 192); \
    B##S##_20 = *(const short8*)(bb2 + _ko +   0); \
    B##S##_21 = *(const short8*)(bb2 + _ko +  64); \
    B##S##_22 = *(const short8*)(bb2 + _ko + 128); \
    B##S##_23 = *(const short8*)(bb2 + _ko + 192); \
    B##S##_30 = *(const short8*)(bb3 + _ko +   0); \
    B##S##_31 = *(const short8*)(bb3 + _ko +  64); \
    B##S##_32 = *(const short8*)(bb3 + _ko + 128); \
    B##S##_33 = *(const short8*)(bb3 + _ko + 192); \
  } while(0)

#define ISSUEA(K) do { \
    const int _kc = (K); \
    char* _dst = lds + (size_t)(_kc & 3) * 32768; \
    _Pragma("unroll") \
    for (int _c = 0; _c < 4; _c++){ \
      int _o = _c * 8192 + tid * 16; \
      int _m = _o >> 9; \
      int _swb = (_o & 511) ^ ((_m & 7) << 4); \
      GL16((const char*)x + (size_t)(row0 + _m) * 16384 + (size_t)_kc * 512 + _swb, _dst + _o); \
    } } while(0)

#define MF1(S, KS) \
    acc[0][0] = __builtin_amdgcn_mfma_f32_16x16x32_bf16(af[0][KS], B##S##_0##KS, acc[0][0], 0, 0, 0); \
    acc[0][1] = __builtin_amdgcn_mfma_f32_16x16x32_bf16(af[0][KS], B##S##_1##KS, acc[0][1], 0, 0, 0); \
    acc[0][2] = __builtin_amdgcn_mfma_f32_16x16x32_bf16(af[0][KS], B##S##_2##KS, acc[0][2], 0, 0, 0); \
    acc[0][3] = __builtin_amdgcn_mfma_f32_16x16x32_bf16(af[0][KS], B##S##_3##KS, acc[0][3], 0, 0, 0); \
    acc[1][0] = __builtin_amdgcn_mfma_f32_16x16x32_bf16(af[1][KS], B##S##_0##KS, acc[1][0], 0, 0, 0); \
    acc[1][1] = __builtin_amdgcn_mfma_f32_16x16x32_bf16(af[1][KS], B##S##_1##KS, acc[1][1], 0, 0, 0); \
    acc[1][2] = __builtin_amdgcn_mfma_f32_16x16x32_bf16(af[1][KS], B##S##_2##KS, acc[1][2], 0, 0, 0); \
    acc[1][3] = __builtin_amdgcn_mfma_f32_16x16x32_bf16(af[1][KS], B##S##_3##KS, acc[1][3], 0, 0, 0);

#define COMPUTE(KI, S) do { \
    const char* _ab = lds + (size_t)((KI) & 3) * 32768; \
    short8 af[2][4]; \
    _Pragma("unroll") \
    for (int _fm = 0; _fm < 2; _fm++){ \
      int _m = wm * 32 + _fm * 16 + cl; \
      int _sw = (_m & 7) << 4; \
      _Pragma("unroll") \
      for (int _ks = 0; _ks < 4; _ks++){ \
        int _ba = _m * 512 + _ks * 128 + g * 32; \
        f4 _lo = *(const f4*)(_ab + ((_ba     ) ^ _sw)); \
        f4 _hi = *(const f4*)(_ab + ((_ba + 16) ^ _sw)); \
        u4 _pk; \
        _pk.x = f2bf(_lo[0]) | (f2bf(_lo[1]) << 16); \
        _pk.y = f2bf(_lo[2]) | (f2bf(_lo[3]) << 16); \
        _pk.z = f2bf(_hi[0]) | (f2bf(_hi[1]) << 16); \
        _pk.w = f2bf(_hi[2]) | (f2bf(_hi[3]) << 16); \
        af[_fm][_ks] = *(short8*)&_pk; \
      } \
    } \
    MF1(S, 0) \
    MF1(S, 1) \
    MF1(S, 2) \
    MF1(S, 3) \
  } while(0)

  // prologue: B(0) (oldest), A(0..2); wait A(0) -> keeps A(1),A(2) in flight
  ISSUEB(0, 0);
  ISSUEA(0); ISSUEA(1); ISSUEA(2);
  VBAR(8);

  #pragma unroll 1
  for (int kk = 0; kk < 32; kk += 2){
    // step kk (even): uses B set0 = B(kk), LDS buf kk&3
    ISSUEB(1, (kk + 1 < 32) ? kk + 1 : 31);          // B first (older than this step's A)
    ISSUEA((kk + 3 < 32) ? kk + 3 : 31);             // A last (newest) — deep prefetch
    SB0;
    COMPUTE(kk, 0);
    SB0;
    VBAR(24);                                        // waits A(kk+1) only
    // step kk+1 (odd): uses B set1 = B(kk+1), LDS buf (kk+1)&3
    ISSUEB(0, (kk + 2 < 32) ? kk + 2 : 31);
    ISSUEA((kk + 4 < 32) ? kk + 4 : 31);
    SB0;
    COMPUTE(kk + 1, 1);
    SB0;
    VBAR(24);
  }
  asm volatile("s_waitcnt vmcnt(0)" ::: "memory");   // drain dummy tail issues

#undef COMPUTE
#undef MF1
#undef ISSUEA
#undef ISSUEB

  // epilogue: bf16 h1 write + fused transposed column stats (per block,wm partials)
  #pragma unroll
  for (int fn = 0; fn < 4; fn++){
    int c = wn * 64 + fn * 16 + cl;
    float sb = fsign(b1[c]);
    float s = 0.f, q = 0.f;
    #pragma unroll
    for (int fm = 0; fm < 2; fm++){
      int rbase = row0 + wm * 32 + fm * 16 + g * 4;
      #pragma unroll
      for (int i = 0; i < 4; i++){
        float v = acc[fm][fn][i] + sb;
        h1[(size_t)(rbase + i) * 256 + c] = (unsigned short)f2bf(v);
        s += v; q += v * v;
      }
    }
    s += __shfl_xor(s, 16, 64); s += __shfl_xor(s, 32, 64);
    q += __shfl_xor(q, 16, 64); q += __shfl_xor(q, 32, 64);
    if (g == 0){
      part1s[(size_t)c * 512 + blockIdx.x * 2 + wm] = s;
      part1q[(size_t)c * 512 + blockIdx.x * 2 + wm] = q;
    }
  }
}

// ---------------- BN params from transposed partials ------------------------------------------
template<int COLS, int NBLK>
__global__ __launch_bounds__(64) void params_k(
    const float* __restrict__ ps, const float* __restrict__ pq,
    const float* __restrict__ g, const float* __restrict__ be,
    float* __restrict__ ab){
  int j = blockIdx.x * 64 + threadIdx.x;
  const f4* vs = (const f4*)(ps + (size_t)j * NBLK);
  const f4* vq = (const f4*)(pq + (size_t)j * NBLK);
  f4 s4 = {0,0,0,0}, q4 = {0,0,0,0};
  #pragma unroll 8
  for (int b = 0; b < NBLK/4; b++){ s4 += vs[b]; q4 += vq[b]; }
  float s = s4[0]+s4[1]+s4[2]+s4[3];
  float q = q4[0]+q4[1]+q4[2]+q4[3];
  float mu  = s * (1.f/16384.f);
  float var = q * (1.f/16384.f) - mu*mu;
  float a   = g[j] * rsqrtf(var + 1e-5f);
  ab[j] = a;
  ab[COLS + j] = be[j] - mu*a;
}

// ---------------- GEMM2: h2(bf16) = clip(BN1(h1)) @ signW2^T + sign(b2), fused stats -----------
__global__ __launch_bounds__(512) void gemm2_k(
    const unsigned short* __restrict__ h1, const unsigned short* __restrict__ w2s,
    const float* __restrict__ b2, const float* __restrict__ ab1,
    unsigned short* __restrict__ h2, float* __restrict__ part2s, float* __restrict__ part2q)
{
  __shared__ __align__(16) char lds[32768];
  __shared__ __align__(16) float a1l[256];
  __shared__ __align__(16) float c1l[256];
  const int tid  = threadIdx.x;
  const int lane = tid & 63;
  const int wid  = tid >> 6;          // 0..7 -> cols wid*16..+15
  const int cl   = lane & 15;
  const int g    = lane >> 4;
  const int klo  = g * 8;
  const int row0 = blockIdx.x * 64;

  if (tid < 256) a1l[tid] = ab1[tid];
  else           c1l[tid - 256] = ab1[tid];

  const int am  = tid >> 3;
  const int ak0 = (tid & 7) * 8;
  const unsigned short* hA = h1 + (size_t)(row0 + am) * 256 + ak0;
  const int aw = ((am * 128) + (ak0 * 2)) ^ ((am & 7) << 4);
  const unsigned short* wbase = w2s + (size_t)(wid * 16 + cl) * 256 + klo;

  u4 q0 = *(const u4*)(hA);
  u4 q1 = *(const u4*)(hA + 64);
  u4 q2 = *(const u4*)(hA + 128);
  u4 q3 = *(const u4*)(hA + 192);
  short8 Bq0, Bq1, Br0, Br1;
  Bq0 = *(const short8*)(wbase);
  Bq1 = *(const short8*)(wbase + 32);

  BARRIER();                 // a1l/c1l visible

#define TRW(KB, RAW) do { \
    f4 _a0 = *(const f4*)(&a1l[(KB)*64 + ak0]); \
    f4 _a1 = *(const f4*)(&a1l[(KB)*64 + ak0 + 4]); \
    f4 _c0 = *(const f4*)(&c1l[(KB)*64 + ak0]); \
    f4 _c1 = *(const f4*)(&c1l[(KB)*64 + ak0 + 4]); \
    float _t0 = hclip(_a0[0]*bflo(RAW.x) + _c0[0]); \
    float _t1 = hclip(_a0[1]*bfhi(RAW.x) + _c0[1]); \
    float _t2 = hclip(_a0[2]*bflo(RAW.y) + _c0[2]); \
    float _t3 = hclip(_a0[3]*bfhi(RAW.y) + _c0[3]); \
    float _t4 = hclip(_a1[0]*bflo(RAW.z) + _c1[0]); \
    float _t5 = hclip(_a1[1]*bfhi(RAW.z) + _c1[1]); \
    float _t6 = hclip(_a1[2]*bflo(RAW.w) + _c1[2]); \
    float _t7 = hclip(_a1[3]*bfhi(RAW.w) + _c1[3]); \
    u4 _v; \
    _v.x = f2bf(_t0) | (f2bf(_t1) << 16); \
    _v.y = f2bf(_t2) | (f2bf(_t3) << 16); \
    _v.z = f2bf(_t4) | (f2bf(_t5) << 16); \
    _v.w = f2bf(_t6) | (f2bf(_t7) << 16); \
    *(u4*)(lds + (KB)*8192 + aw) = _v; \
  } while(0)

  TRW(0, q0); TRW(1, q1); TRW(2, q2); TRW(3, q3);
#undef TRW
  BARRIER();

  f4 acc[4];
  const f4 z = {0.f, 0.f, 0.f, 0.f};
  #pragma unroll
  for (int i = 0; i < 4; i++) acc[i] = z;

#define LOADB2(P, KB) do { \
    B##P##0 = *(const short8*)(wbase + (KB)*64); \
    B##P##1 = *(const short8*)(wbase + (KB)*64 + 32); \
  } while(0)

#define COMP2(BASE, P) do { \
    const char* _ab = (const char*)(BASE); \
    short8 _af[4][2]; \
    _Pragma("unroll") \
    for (int fm = 0; fm < 4; fm++){ \
      int _m = fm*16 + cl; \
      _af[fm][0] = *(const short8*)(_ab + ((_m*128 + klo*2) ^ ((_m & 7) << 4))); \
      _af[fm][1] = *(const short8*)(_ab + ((_m*128 + (32 + klo)*2) ^ ((_m & 7) << 4))); \
    } \
    _Pragma("unroll") \
    for (int fm = 0; fm < 4; fm++){ \
      acc[fm] = __builtin_amdgcn_mfma_f32_16x16x32_bf16(_af[fm][0], B##P##0, acc[fm], 0, 0, 0); \
      acc[fm] = __builtin_amdgcn_mfma_f32_16x16x32_bf16(_af[fm][1], B##P##1, acc[fm], 0, 0, 0); \
    } \
  } while(0)

  LOADB2(r, 1);
  COMP2(lds,         q);
  LOADB2(q, 2);
  COMP2(lds +  8192, r);
  LOADB2(r, 3);
  COMP2(lds + 16384, q);
  COMP2(lds + 24576, r);
#undef COMP2
#undef LOADB2

  {
    int c = wid*16 + cl;
    float sb = fsign(b2[c]);
    float s = 0.f, q = 0.f;
    #pragma unroll
    for (int fm = 0; fm < 4; fm++){
      int rbase = row0 + fm*16 + g*4;
      #pragma unroll
      for (int i = 0; i < 4; i++){
        float v = acc[fm][i] + sb;
        h2[(size_t)(rbase + i)*128 + c] = (unsigned short)f2bf(v);
        s += v; q += v*v;
      }
    }
    s += __shfl_xor(s, 16, 64); s += __shfl_xor(s, 32, 64);
    q += __shfl_xor(q, 16, 64); q += __shfl_xor(q, 32, 64);
    if (g == 0){
      part2s[c*256 + blockIdx.x] = s;
      part2q[c*256 + blockIdx.x] = q;
    }
  }
}

// ---------------- final: out = clip(BN2(h2)) @ W4^T + b4, BN2 params fused ---------------------
__global__ __launch_bounds__(128) void final_k(
    const unsigned short* __restrict__ h2,
    const float* __restrict__ part2s, const float* __restrict__ part2q,
    const float* __restrict__ g2, const float* __restrict__ be2,
    const float* __restrict__ W4, const float* __restrict__ b4,
    float* __restrict__ out)
{
  __shared__ __align__(16) float W4l[12*128];
  __shared__ __align__(16) float a2l[128];
  __shared__ __align__(16) float c2l[128];
  const int t = threadIdx.x;
  #pragma unroll
  for (int i = 0; i < 3; i++)
    *(f4*)&W4l[(i*128 + t)*4] = *(const f4*)(W4 + (i*128 + t)*4);
  {
    const f4* vs = (const f4*)(part2s + t*256);
    const f4* vq = (const f4*)(part2q + t*256);
    f4 s4 = {0,0,0,0}, q4 = {0,0,0,0};
    #pragma unroll 8
    for (int b = 0; b < 64; b++){ s4 += vs[b]; q4 += vq[b]; }
    float s = s4[0]+s4[1]+s4[2]+s4[3];
    float q = q4[0]+q4[1]+q4[2]+q4[3];
    float mu  = s * (1.f/16384.f);
    float var = q * (1.f/16384.f) - mu*mu;
    float a   = g2[t] * rsqrtf(var + 1e-5f);
    a2l[t] = a;
    c2l[t] = be2[t] - mu*a;
  }
  __syncthreads();

  const int r = blockIdx.x * 128 + t;
  const u4* hp = (const u4*)(h2 + (size_t)r * 128);
  u4 hv0 = hp[0], hv1 = hp[1], hv2 = hp[2],  hv3 = hp[3];
  u4 hv4 = hp[4], hv5 = hp[5], hv6 = hp[6],  hv7 = hp[7];
  u4 hv8 = hp[8], hv9 = hp[9], hv10 = hp[10], hv11 = hp[11];
  u4 hv12 = hp[12], hv13 = hp[13], hv14 = hp[14], hv15 = hp[15];

  float acc[12];
  #pragma unroll
  for (int o = 0; o < 12; o++) acc[o] = b4[o];

#define FPROC(HV, J) do { \
    f4 a0 = *(const f4*)&a2l[(J)*8];     f4 a1 = *(const f4*)&a2l[(J)*8 + 4]; \
    f4 c0 = *(const f4*)&c2l[(J)*8];     f4 c1 = *(const f4*)&c2l[(J)*8 + 4]; \
    float tt0 = hclip(a0[0]*bflo(HV.x) + c0[0]); \
    float tt1 = hclip(a0[1]*bfhi(HV.x) + c0[1]); \
    float tt2 = hclip(a0[2]*bflo(HV.y) + c0[2]); \
    float tt3 = hclip(a0[3]*bfhi(HV.y) + c0[3]); \
    float tt4 = hclip(a1[0]*bflo(HV.z) + c1[0]); \
    float tt5 = hclip(a1[1]*bfhi(HV.z) + c1[1]); \
    float tt6 = hclip(a1[2]*bflo(HV.w) + c1[2]); \
    float tt7 = hclip(a1[3]*bfhi(HV.w) + c1[3]); \
    _Pragma("unroll") \
    for (int o = 0; o < 12; o++){ \
      f4 w0 = *(const f4*)&W4l[o*128 + (J)*8]; \
      f4 w1 = *(const f4*)&W4l[o*128 + (J)*8 + 4]; \
      acc[o] += tt0*w0[0] + tt1*w0[1] + tt2*w0[2] + tt3*w0[3] \
              + tt4*w1[0] + tt5*w1[1] + tt6*w1[2] + tt7*w1[3]; \
    } \
  } while(0)

  FPROC(hv0, 0);  FPROC(hv1, 1);  FPROC(hv2, 2);   FPROC(hv3, 3);
  FPROC(hv4, 4);  FPROC(hv5, 5);  FPROC(hv6, 6);   FPROC(hv7, 7);
  FPROC(hv8, 8);  FPROC(hv9, 9);  FPROC(hv10, 10); FPROC(hv11, 11);
  FPROC(hv12, 12); FPROC(hv13, 13); FPROC(hv14, 14); FPROC(hv15, 15);
#undef FPROC

  #pragma unroll
  for (int o = 0; o < 12; o++) out[(size_t)r*12 + o] = acc[o];
}

// ---------------- launch ----------------
extern "C" void kernel_launch(void* const* d_in, const int* in_sizes, int n_in,
                              void* d_out, int out_size, void* d_ws, size_t ws_size,
                              hipStream_t stream)
{
  const float* x   = (const float*)d_in[0];
  const float* W1  = (const float*)d_in[1];
  const float* b1  = (const float*)d_in[2];
  const float* g1  = (const float*)d_in[3];
  const float* be1 = (const float*)d_in[4];
  const float* W2  = (const float*)d_in[5];
  const float* b2  = (const float*)d_in[6];
  const float* g2  = (const float*)d_in[7];
  const float* be2 = (const float*)d_in[8];
  const float* W4  = (const float*)d_in[9];
  const float* b4  = (const float*)d_in[10];
  float* out = (float*)d_out;

  char* ws = (char*)d_ws;
  unsigned short* h1     = (unsigned short*)(ws);              //  8 MB  [16384,256] bf16
  unsigned short* h2     = (unsigned short*)(ws + 8388608);    //  4 MB  [16384,128] bf16
  unsigned short* w1s    = (unsigned short*)(ws + 12582912);   //  2 MB  [256,4096] bf16
  unsigned short* w2s    = (unsigned short*)(ws + 14680064);   // 64 KB  [128,256] bf16
  float*          part1s = (float*)(ws + 14745600);            // 512 KB [256][512]
  float*          part1q = (float*)(ws + 15269888);            // 512 KB
  float*          part2s = (float*)(ws + 15794176);            // 128 KB [128][256]
  float*          part2q = (float*)(ws + 15925248);            // 128 KB
  float*          ab1    = (float*)(ws + 16056320);            // a1[256], c1[256]

  prep_sign_k<<<528, 256, 0, stream>>>(W1, w1s, W2, w2s);
  gemm1_k<<<256, 512, 0, stream>>>(x, w1s, b1, h1, part1s, part1q);
  params_k<256, 512><<<4, 64, 0, stream>>>(part1s, part1q, g1, be1, ab1);
  gemm2_k<<<256, 512, 0, stream>>>(h1, w2s, b2, ab1, h2, part2s, part2q);
  final_k<<<128, 128, 0, stream>>>(h2, part2s, part2q, g2, be2, W4, b4, out);
}

// Round 13
// 147.795 us; speedup vs baseline: 1.4706x; 1.4706x over previous
//
#include <hip/hip_runtime.h>
#include <cstddef>

typedef __attribute__((ext_vector_type(8))) short short8;
typedef __attribute__((ext_vector_type(4))) float f4;
typedef __attribute__((ext_vector_type(4))) unsigned int u4;
typedef __attribute__((ext_vector_type(2))) unsigned int u2;

__device__ __forceinline__ unsigned int f2bf(float f){
  unsigned int u = __float_as_uint(f);
  u += 0x7fffu + ((u >> 16) & 1u);   // RNE to bf16
  return u >> 16;
}
__device__ __forceinline__ float bflo(unsigned int w){ return __uint_as_float((w & 0xFFFFu) << 16); }
__device__ __forceinline__ float bfhi(unsigned int w){ return __uint_as_float(w & 0xFFFF0000u); }
__device__ __forceinline__ float fsign(float x){ return (x > 0.f) ? 1.f : ((x < 0.f) ? -1.f : 0.f); }
__device__ __forceinline__ float hclip(float x){ return fminf(1.f, fmaxf(-1.f, x)); }

#define SB0 __builtin_amdgcn_sched_barrier(0)

// lgkm-only barrier (vmem loads stay in flight)
#define BARRIER() do { \
    SB0; \
    asm volatile("s_waitcnt lgkmcnt(0)" ::: "memory"); \
    __builtin_amdgcn_s_barrier(); \
    asm volatile("" ::: "memory"); \
    SB0; \
  } while(0)

// counted-vmcnt barrier: drain all but N newest vmem ops, then workgroup barrier
#define VBAR(N) do { \
    SB0; \
    asm volatile("s_waitcnt vmcnt(" #N ") lgkmcnt(0)" ::: "memory"); \
    __builtin_amdgcn_s_barrier(); \
    asm volatile("" ::: "memory"); \
    SB0; \
  } while(0)

// global -> LDS direct DMA, 16B per lane
#define GL16(gp, lp) __builtin_amdgcn_global_load_lds( \
    (const __attribute__((address_space(1))) void*)(gp), \
    (__attribute__((address_space(3))) void*)(lp), 16, 0, 0)

// ---------------- prep: sign(W1)+sign(W2) fp32 -> bf16 {+1,-1,0}, one dispatch ----------------
__global__ void prep_sign_k(const float* __restrict__ W1, unsigned short* __restrict__ w1s,
                            const float* __restrict__ W2, unsigned short* __restrict__ w2s){
  int i = (blockIdx.x * blockDim.x + threadIdx.x) * 8;
  const float* w; unsigned short* o; int off;
  if (i < 1048576){ w = W1; o = w1s; off = i; }
  else            { w = W2; o = w2s; off = i - 1048576; if (off >= 32768) return; }
  f4 a = *(const f4*)(w + off);
  f4 b = *(const f4*)(w + off + 4);
  unsigned short s[8];
  #pragma unroll
  for (int j = 0; j < 4; j++) s[j]   = (a[j] > 0.f) ? 0x3F80u : ((a[j] < 0.f) ? 0xBF80u : 0u);
  #pragma unroll
  for (int j = 0; j < 4; j++) s[4+j] = (b[j] > 0.f) ? 0x3F80u : ((b[j] < 0.f) ? 0xBF80u : 0u);
  u4 v;
  v.x = (unsigned)s[0] | ((unsigned)s[1] << 16);
  v.y = (unsigned)s[2] | ((unsigned)s[3] << 16);
  v.z = (unsigned)s[4] | ((unsigned)s[5] << 16);
  v.w = (unsigned)s[6] | ((unsigned)s[7] << 16);
  *(u4*)(o + off) = v;
}

// ---------------- GEMM1: h1(bf16) = x @ signW1^T + sign(b1), fused transposed col-stats ---------
// BM=64, BN=256, BK=32, 128 K-steps. 512 thr = 8 waves, wave tile 32x64.
// LDS 74KB -> 2 blocks/CU (launch_bounds(512,4)): anti-phase block covers barrier drains.
// A: f4 reg-load (depth-3, 4 rotating sets) -> f2bf once -> ds_write_b64 into padded
//    (stride 80B, conflict-free) bf16 dbuf 2x5KB. B: 2 GL16/step into 4x16KB bufs,
//    depth-2, source-XOR swizzle (n&3)<<4. Ledger: per step issue {B(k+2)x2, A(k+3)};
//    VBAR(4) keeps {A(k+2), B(k+2)x2, A(k+3)} in flight -> A slack 2 steps, B slack 1.
__global__ __launch_bounds__(512, 4) void gemm1_k(
    const float* __restrict__ x, const unsigned short* __restrict__ w1s,
    const float* __restrict__ b1, unsigned short* __restrict__ h1,
    float* __restrict__ part1s, float* __restrict__ part1q)
{
  __shared__ __align__(16) char lds[75776];   // A: 2x5120 @0 ; B: 4x16384 @10240
  const int tid  = threadIdx.x;
  const int lane = tid & 63;
  const int wid  = tid >> 6;
  const int wm   = wid >> 2;          // 0..1 -> rows wm*32..+31
  const int wn   = wid & 3;           // 0..3 -> cols wn*64..+63
  const int cl   = lane & 15;
  const int g    = lane >> 4;         // 0..3
  const int row0 = blockIdx.x * 64;

  // A reg-staging: thread -> row tid>>3 (0..63), 4 contiguous fp32 at (tid&7)*4
  const float* xA = x + (size_t)(row0 + (tid >> 3)) * 4096 + (tid & 7) * 4;
  const int aw = (tid >> 3) * 80 + (tid & 7) * 8;          // padded stride 80B

  // B staging: 2 GL16/thread; linear dest o = c*8192 + tid*16; src XOR (n&3)<<4
  const int n0  = (tid >> 2);              // c=0 rows 0..127
  const int sb0 = ((tid & 3) * 16) ^ ((n0 & 3) << 4);
  const int n1  = 128 + (tid >> 2);        // c=1 rows 128..255
  const int sb1 = ((tid & 3) * 16) ^ ((n1 & 3) << 4);
  const char* srcB0 = (const char*)w1s + (size_t)n0 * 8192 + sb0;
  const char* srcB1 = (const char*)w1s + (size_t)n1 * 8192 + sb1;
  const int dstB0 = tid * 16;
  const int dstB1 = 8192 + tid * 16;

  // frag read offsets (precomputed)
  int afo[2], bfo[4];
  #pragma unroll
  for (int fm = 0; fm < 2; fm++)
    afo[fm] = (wm * 32 + fm * 16 + cl) * 80 + g * 16;
  #pragma unroll
  for (int fn = 0; fn < 4; fn++){
    int n = wn * 64 + fn * 16 + cl;
    bfo[fn] = n * 64 + ((g * 16) ^ ((n & 3) << 4));
  }

  f4 acc[2][4];
  const f4 z = {0.f, 0.f, 0.f, 0.f};
  #pragma unroll
  for (int i = 0; i < 2; i++)
    #pragma unroll
    for (int j = 0; j < 4; j++) acc[i][j] = z;

  f4 rA0, rA1, rA2, rA3;   // 4 rotating A reg sets

#define ISSUEA(S, K) do { rA##S = *(const f4*)(xA + (size_t)(K) * 32); } while(0)

#define ISSUEB(BI, K) do { \
    GL16(srcB0 + (size_t)(K) * 64, lds + 10240 + (BI) * 16384 + dstB0); \
    GL16(srcB1 + (size_t)(K) * 64, lds + 10240 + (BI) * 16384 + dstB1); \
  } while(0)

#define PACKA(S, AB) do { \
    u2 _v; \
    _v.x = f2bf(rA##S[0]) | (f2bf(rA##S[1]) << 16); \
    _v.y = f2bf(rA##S[2]) | (f2bf(rA##S[3]) << 16); \
    *(u2*)(lds + (AB) * 5120 + aw) = _v; \
  } while(0)

#define COMPUTE(AB, BB) do { \
    const char* _ab = lds + (AB) * 5120; \
    const char* _bb = lds + 10240 + (BB) * 16384; \
    short8 _af0 = *(const short8*)(_ab + afo[0]); \
    short8 _af1 = *(const short8*)(_ab + afo[1]); \
    short8 _bf0 = *(const short8*)(_bb + bfo[0]); \
    short8 _bf1 = *(const short8*)(_bb + bfo[1]); \
    short8 _bf2 = *(const short8*)(_bb + bfo[2]); \
    short8 _bf3 = *(const short8*)(_bb + bfo[3]); \
    __builtin_amdgcn_s_setprio(1); \
    acc[0][0] = __builtin_amdgcn_mfma_f32_16x16x32_bf16(_af0, _bf0, acc[0][0], 0, 0, 0); \
    acc[0][1] = __builtin_amdgcn_mfma_f32_16x16x32_bf16(_af0, _bf1, acc[0][1], 0, 0, 0); \
    acc[0][2] = __builtin_amdgcn_mfma_f32_16x16x32_bf16(_af0, _bf2, acc[0][2], 0, 0, 0); \
    acc[0][3] = __builtin_amdgcn_mfma_f32_16x16x32_bf16(_af0, _bf3, acc[0][3], 0, 0, 0); \
    acc[1][0] = __builtin_amdgcn_mfma_f32_16x16x32_bf16(_af1, _bf0, acc[1][0], 0, 0, 0); \
    acc[1][1] = __builtin_amdgcn_mfma_f32_16x16x32_bf16(_af1, _bf1, acc[1][1], 0, 0, 0); \
    acc[1][2] = __builtin_amdgcn_mfma_f32_16x16x32_bf16(_af1, _bf2, acc[1][2], 0, 0, 0); \
    acc[1][3] = __builtin_amdgcn_mfma_f32_16x16x32_bf16(_af1, _bf3, acc[1][3], 0, 0, 0); \
    __builtin_amdgcn_s_setprio(0); \
  } while(0)

// one K-step (all indices compile-time via unroll-4): issue B(K+2), A(K+3);
// compute(K); pack A(K+1); VBAR(4) -> {A(K+2), B(K+2)x2, A(K+3)} stay in flight.
#define STEP(K, BI2, AI3, AP1, ABR, ABW) do { \
    ISSUEB(BI2, ((K)+2 < 128) ? (K)+2 : 127); \
    ISSUEA(AI3, ((K)+3 < 128) ? (K)+3 : 127); \
    SB0; \
    COMPUTE(ABR, (K) & 3); \
    SB0; \
    if ((K) < 127) PACKA(AP1, ABW); \
    VBAR(4); \
  } while(0)

  // prologue: B(0),B(1) + A(0),A(1),A(2); pack A(0) (drains B(0)); barrier
  ISSUEB(0, 0); ISSUEA(0, 0);
  ISSUEB(1, 1); ISSUEA(1, 1);
  ISSUEA(2, 2);
  SB0;
  PACKA(0, 0);          // compiler vmcnt wait on A(0) -> drains B(0)x2, keeps 4 newest
  BARRIER();

  #pragma unroll 1
  for (int kk = 0; kk < 128; kk += 4){
    STEP(kk + 0, 2, 3, 1, 0, 1);
    STEP(kk + 1, 3, 0, 2, 1, 0);
    STEP(kk + 2, 0, 1, 3, 0, 1);
    STEP(kk + 3, 1, 2, 0, 1, 0);
  }
  asm volatile("s_waitcnt vmcnt(0)" ::: "memory");

#undef STEP
#undef COMPUTE
#undef PACKA
#undef ISSUEB
#undef ISSUEA

  // epilogue: bf16 h1 write + fused transposed column stats (per block,wm partials)
  #pragma unroll
  for (int fn = 0; fn < 4; fn++){
    int c = wn * 64 + fn * 16 + cl;
    float sb = fsign(b1[c]);
    float s = 0.f, q = 0.f;
    #pragma unroll
    for (int fm = 0; fm < 2; fm++){
      int rbase = row0 + wm * 32 + fm * 16 + g * 4;
      #pragma unroll
      for (int i = 0; i < 4; i++){
        float v = acc[fm][fn][i] + sb;
        h1[(size_t)(rbase + i) * 256 + c] = (unsigned short)f2bf(v);
        s += v; q += v * v;
      }
    }
    s += __shfl_xor(s, 16, 64); s += __shfl_xor(s, 32, 64);
    q += __shfl_xor(q, 16, 64); q += __shfl_xor(q, 32, 64);
    if (g == 0){
      part1s[(size_t)c * 512 + blockIdx.x * 2 + wm] = s;
      part1q[(size_t)c * 512 + blockIdx.x * 2 + wm] = q;
    }
  }
}

// ---------------- BN params from transposed partials ------------------------------------------
template<int COLS, int NBLK>
__global__ __launch_bounds__(64) void params_k(
    const float* __restrict__ ps, const float* __restrict__ pq,
    const float* __restrict__ g, const float* __restrict__ be,
    float* __restrict__ ab){
  int j = blockIdx.x * 64 + threadIdx.x;
  const f4* vs = (const f4*)(ps + (size_t)j * NBLK);
  const f4* vq = (const f4*)(pq + (size_t)j * NBLK);
  f4 s4 = {0,0,0,0}, q4 = {0,0,0,0};
  #pragma unroll 8
  for (int b = 0; b < NBLK/4; b++){ s4 += vs[b]; q4 += vq[b]; }
  float s = s4[0]+s4[1]+s4[2]+s4[3];
  float q = q4[0]+q4[1]+q4[2]+q4[3];
  float mu  = s * (1.f/16384.f);
  float var = q * (1.f/16384.f) - mu*mu;
  float a   = g[j] * rsqrtf(var + 1e-5f);
  ab[j] = a;
  ab[COLS + j] = be[j] - mu*a;
}

// ---------------- GEMM2: h2(bf16) = clip(BN1(h1)) @ signW2^T + sign(b2), fused stats -----------
__global__ __launch_bounds__(512) void gemm2_k(
    const unsigned short* __restrict__ h1, const unsigned short* __restrict__ w2s,
    const float* __restrict__ b2, const float* __restrict__ ab1,
    unsigned short* __restrict__ h2, float* __restrict__ part2s, float* __restrict__ part2q)
{
  __shared__ __align__(16) char lds[32768];
  __shared__ __align__(16) float a1l[256];
  __shared__ __align__(16) float c1l[256];
  const int tid  = threadIdx.x;
  const int lane = tid & 63;
  const int wid  = tid >> 6;          // 0..7 -> cols wid*16..+15
  const int cl   = lane & 15;
  const int g    = lane >> 4;
  const int klo  = g * 8;
  const int row0 = blockIdx.x * 64;

  if (tid < 256) a1l[tid] = ab1[tid];
  else           c1l[tid - 256] = ab1[tid];

  const int am  = tid >> 3;
  const int ak0 = (tid & 7) * 8;
  const unsigned short* hA = h1 + (size_t)(row0 + am) * 256 + ak0;
  const int aw = ((am * 128) + (ak0 * 2)) ^ ((am & 7) << 4);
  const unsigned short* wbase = w2s + (size_t)(wid * 16 + cl) * 256 + klo;

  u4 q0 = *(const u4*)(hA);
  u4 q1 = *(const u4*)(hA + 64);
  u4 q2 = *(const u4*)(hA + 128);
  u4 q3 = *(const u4*)(hA + 192);
  short8 Bq0, Bq1, Br0, Br1;
  Bq0 = *(const short8*)(wbase);
  Bq1 = *(const short8*)(wbase + 32);

  BARRIER();                 // a1l/c1l visible

#define TRW(KB, RAW) do { \
    f4 _a0 = *(const f4*)(&a1l[(KB)*64 + ak0]); \
    f4 _a1 = *(const f4*)(&a1l[(KB)*64 + ak0 + 4]); \
    f4 _c0 = *(const f4*)(&c1l[(KB)*64 + ak0]); \
    f4 _c1 = *(const f4*)(&c1l[(KB)*64 + ak0 + 4]); \
    float _t0 = hclip(_a0[0]*bflo(RAW.x) + _c0[0]); \
    float _t1 = hclip(_a0[1]*bfhi(RAW.x) + _c0[1]); \
    float _t2 = hclip(_a0[2]*bflo(RAW.y) + _c0[2]); \
    float _t3 = hclip(_a0[3]*bfhi(RAW.y) + _c0[3]); \
    float _t4 = hclip(_a1[0]*bflo(RAW.z) + _c1[0]); \
    float _t5 = hclip(_a1[1]*bfhi(RAW.z) + _c1[1]); \
    float _t6 = hclip(_a1[2]*bflo(RAW.w) + _c1[2]); \
    float _t7 = hclip(_a1[3]*bfhi(RAW.w) + _c1[3]); \
    u4 _v; \
    _v.x = f2bf(_t0) | (f2bf(_t1) << 16); \
    _v.y = f2bf(_t2) | (f2bf(_t3) << 16); \
    _v.z = f2bf(_t4) | (f2bf(_t5) << 16); \
    _v.w = f2bf(_t6) | (f2bf(_t7) << 16); \
    *(u4*)(lds + (KB)*8192 + aw) = _v; \
  } while(0)

  TRW(0, q0); TRW(1, q1); TRW(2, q2); TRW(3, q3);
#undef TRW
  BARRIER();

  f4 acc[4];
  const f4 z = {0.f, 0.f, 0.f, 0.f};
  #pragma unroll
  for (int i = 0; i < 4; i++) acc[i] = z;

#define LOADB2(P, KB) do { \
    B##P##0 = *(const short8*)(wbase + (KB)*64); \
    B##P##1 = *(const short8*)(wbase + (KB)*64 + 32); \
  } while(0)

#define COMP2(BASE, P) do { \
    const char* _ab = (const char*)(BASE); \
    short8 _af[4][2]; \
    _Pragma("unroll") \
    for (int fm = 0; fm < 4; fm++){ \
      int _m = fm*16 + cl; \
      _af[fm][0] = *(const short8*)(_ab + ((_m*128 + klo*2) ^ ((_m & 7) << 4))); \
      _af[fm][1] = *(const short8*)(_ab + ((_m*128 + (32 + klo)*2) ^ ((_m & 7) << 4))); \
    } \
    _Pragma("unroll") \
    for (int fm = 0; fm < 4; fm++){ \
      acc[fm] = __builtin_amdgcn_mfma_f32_16x16x32_bf16(_af[fm][0], B##P##0, acc[fm], 0, 0, 0); \
      acc[fm] = __builtin_amdgcn_mfma_f32_16x16x32_bf16(_af[fm][1], B##P##1, acc[fm], 0, 0, 0); \
    } \
  } while(0)

  LOADB2(r, 1);
  COMP2(lds,         q);
  LOADB2(q, 2);
  COMP2(lds +  8192, r);
  LOADB2(r, 3);
  COMP2(lds + 16384, q);
  COMP2(lds + 24576, r);
#undef COMP2
#undef LOADB2

  {
    int c = wid*16 + cl;
    float sb = fsign(b2[c]);
    float s = 0.f, q = 0.f;
    #pragma unroll
    for (int fm = 0; fm < 4; fm++){
      int rbase = row0 + fm*16 + g*4;
      #pragma unroll
      for (int i = 0; i < 4; i++){
        float v = acc[fm][i] + sb;
        h2[(size_t)(rbase + i)*128 + c] = (unsigned short)f2bf(v);
        s += v; q += v*v;
      }
    }
    s += __shfl_xor(s, 16, 64); s += __shfl_xor(s, 32, 64);
    q += __shfl_xor(q, 16, 64); q += __shfl_xor(q, 32, 64);
    if (g == 0){
      part2s[c*256 + blockIdx.x] = s;
      part2q[c*256 + blockIdx.x] = q;
    }
  }
}

// ---------------- final: out = clip(BN2(h2)) @ W4^T + b4, BN2 params fused ---------------------
__global__ __launch_bounds__(128) void final_k(
    const unsigned short* __restrict__ h2,
    const float* __restrict__ part2s, const float* __restrict__ part2q,
    const float* __restrict__ g2, const float* __restrict__ be2,
    const float* __restrict__ W4, const float* __restrict__ b4,
    float* __restrict__ out)
{
  __shared__ __align__(16) float W4l[12*128];
  __shared__ __align__(16) float a2l[128];
  __shared__ __align__(16) float c2l[128];
  const int t = threadIdx.x;
  #pragma unroll
  for (int i = 0; i < 3; i++)
    *(f4*)&W4l[(i*128 + t)*4] = *(const f4*)(W4 + (i*128 + t)*4);
  {
    const f4* vs = (const f4*)(part2s + t*256);
    const f4* vq = (const f4*)(part2q + t*256);
    f4 s4 = {0,0,0,0}, q4 = {0,0,0,0};
    #pragma unroll 8
    for (int b = 0; b < 64; b++){ s4 += vs[b]; q4 += vq[b]; }
    float s = s4[0]+s4[1]+s4[2]+s4[3];
    float q = q4[0]+q4[1]+q4[2]+q4[3];
    float mu  = s * (1.f/16384.f);
    float var = q * (1.f/16384.f) - mu*mu;
    float a   = g2[t] * rsqrtf(var + 1e-5f);
    a2l[t] = a;
    c2l[t] = be2[t] - mu*a;
  }
  __syncthreads();

  const int r = blockIdx.x * 128 + t;
  const u4* hp = (const u4*)(h2 + (size_t)r * 128);
  u4 hv0 = hp[0], hv1 = hp[1], hv2 = hp[2],  hv3 = hp[3];
  u4 hv4 = hp[4], hv5 = hp[5], hv6 = hp[6],  hv7 = hp[7];
  u4 hv8 = hp[8], hv9 = hp[9], hv10 = hp[10], hv11 = hp[11];
  u4 hv12 = hp[12], hv13 = hp[13], hv14 = hp[14], hv15 = hp[15];

  float acc[12];
  #pragma unroll
  for (int o = 0; o < 12; o++) acc[o] = b4[o];

#define FPROC(HV, J) do { \
    f4 a0 = *(const f4*)&a2l[(J)*8];     f4 a1 = *(const f4*)&a2l[(J)*8 + 4]; \
    f4 c0 = *(const f4*)&c2l[(J)*8];     f4 c1 = *(const f4*)&c2l[(J)*8 + 4]; \
    float tt0 = hclip(a0[0]*bflo(HV.x) + c0[0]); \
    float tt1 = hclip(a0[1]*bfhi(HV.x) + c0[1]); \
    float tt2 = hclip(a0[2]*bflo(HV.y) + c0[2]); \
    float tt3 = hclip(a0[3]*bfhi(HV.y) + c0[3]); \
    float tt4 = hclip(a1[0]*bflo(HV.z) + c1[0]); \
    float tt5 = hclip(a1[1]*bfhi(HV.z) + c1[1]); \
    float tt6 = hclip(a1[2]*bflo(HV.w) + c1[2]); \
    float tt7 = hclip(a1[3]*bfhi(HV.w) + c1[3]); \
    _Pragma("unroll") \
    for (int o = 0; o < 12; o++){ \
      f4 w0 = *(const f4*)&W4l[o*128 + (J)*8]; \
      f4 w1 = *(const f4*)&W4l[o*128 + (J)*8 + 4]; \
      acc[o] += tt0*w0[0] + tt1*w0[1] + tt2*w0[2] + tt3*w0[3] \
              + tt4*w1[0] + tt5*w1[1] + tt6*w1[2] + tt7*w1[3]; \
    } \
  } while(0)

  FPROC(hv0, 0);  FPROC(hv1, 1);  FPROC(hv2, 2);   FPROC(hv3, 3);
  FPROC(hv4, 4);  FPROC(hv5, 5);  FPROC(hv6, 6);   FPROC(hv7, 7);
  FPROC(hv8, 8);  FPROC(hv9, 9);  FPROC(hv10, 10); FPROC(hv11, 11);
  FPROC(hv12, 12); FPROC(hv13, 13); FPROC(hv14, 14); FPROC(hv15, 15);
#undef FPROC

  #pragma unroll
  for (int o = 0; o < 12; o++) out[(size_t)r*12 + o] = acc[o];
}

// ---------------- launch ----------------
extern "C" void kernel_launch(void* const* d_in, const int* in_sizes, int n_in,
                              void* d_out, int out_size, void* d_ws, size_t ws_size,
                              hipStream_t stream)
{
  const float* x   = (const float*)d_in[0];
  const float* W1  = (const float*)d_in[1];
  const float* b1  = (const float*)d_in[2];
  const float* g1  = (const float*)d_in[3];
  const float* be1 = (const float*)d_in[4];
  const float* W2  = (const float*)d_in[5];
  const float* b2  = (const float*)d_in[6];
  const float* g2  = (const float*)d_in[7];
  const float* be2 = (const float*)d_in[8];
  const float* W4  = (const float*)d_in[9];
  const float* b4  = (const float*)d_in[10];
  float* out = (float*)d_out;

  char* ws = (char*)d_ws;
  unsigned short* h1     = (unsigned short*)(ws);              //  8 MB  [16384,256] bf16
  unsigned short* h2     = (unsigned short*)(ws + 8388608);    //  4 MB  [16384,128] bf16
  unsigned short* w1s    = (unsigned short*)(ws + 12582912);   //  2 MB  [256,4096] bf16
  unsigned short* w2s    = (unsigned short*)(ws + 14680064);   // 64 KB  [128,256] bf16
  float*          part1s = (float*)(ws + 14745600);            // 512 KB [256][512]
  float*          part1q = (float*)(ws + 15269888);            // 512 KB
  float*          part2s = (float*)(ws + 15794176);            // 128 KB [128][256]
  float*          part2q = (float*)(ws + 15925248);            // 128 KB
  float*          ab1    = (float*)(ws + 16056320);            // a1[256], c1[256]

  prep_sign_k<<<528, 256, 0, stream>>>(W1, w1s, W2, w2s);
  gemm1_k<<<256, 512, 0, stream>>>(x, w1s, b1, h1, part1s, part1q);
  params_k<256, 512><<<4, 64, 0, stream>>>(part1s, part1q, g1, be1, ab1);
  gemm2_k<<<256, 512, 0, stream>>>(h1, w2s, b2, ab1, h2, part2s, part2q);
  final_k<<<128, 128, 0, stream>>>(h2, part2s, part2q, g2, be2, W4, b4, out);
}

// Round 14
// 116.070 us; speedup vs baseline: 1.8725x; 1.2733x over previous
//
#include <hip/hip_runtime.h>
#include <cstddef>

typedef __attribute__((ext_vector_type(8))) short short8;
typedef __attribute__((ext_vector_type(4))) float f4;
typedef __attribute__((ext_vector_type(4))) unsigned int u4;

__device__ __forceinline__ unsigned int f2bf(float f){
  unsigned int u = __float_as_uint(f);
  u += 0x7fffu + ((u >> 16) & 1u);   // RNE to bf16
  return u >> 16;
}
__device__ __forceinline__ float bflo(unsigned int w){ return __uint_as_float((w & 0xFFFFu) << 16); }
__device__ __forceinline__ float bfhi(unsigned int w){ return __uint_as_float(w & 0xFFFF0000u); }
__device__ __forceinline__ float fsign(float x){ return (x > 0.f) ? 1.f : ((x < 0.f) ? -1.f : 0.f); }
__device__ __forceinline__ float hclip(float x){ return fminf(1.f, fmaxf(-1.f, x)); }

#define SB0 __builtin_amdgcn_sched_barrier(0)

// lgkm-only barrier (vmem loads stay in flight)
#define BARRIER() do { \
    SB0; \
    asm volatile("s_waitcnt lgkmcnt(0)" ::: "memory"); \
    __builtin_amdgcn_s_barrier(); \
    asm volatile("" ::: "memory"); \
    SB0; \
  } while(0)

// counted-vmcnt barrier: drain all but N newest vmem ops, then workgroup barrier
#define VBAR(N) do { \
    SB0; \
    asm volatile("s_waitcnt vmcnt(" #N ") lgkmcnt(0)" ::: "memory"); \
    __builtin_amdgcn_s_barrier(); \
    asm volatile("" ::: "memory"); \
    SB0; \
  } while(0)

// global -> LDS direct DMA, 16B per lane
#define GL16(gp, lp) __builtin_amdgcn_global_load_lds( \
    (const __attribute__((address_space(1))) void*)(gp), \
    (__attribute__((address_space(3))) void*)(lp), 16, 0, 0)

// ---------------- prep: sign(W1)+sign(W2) fp32 -> bf16 {+1,-1,0}, one dispatch ----------------
__global__ void prep_sign_k(const float* __restrict__ W1, unsigned short* __restrict__ w1s,
                            const float* __restrict__ W2, unsigned short* __restrict__ w2s){
  int i = (blockIdx.x * blockDim.x + threadIdx.x) * 8;
  const float* w; unsigned short* o; int off;
  if (i < 1048576){ w = W1; o = w1s; off = i; }
  else            { w = W2; o = w2s; off = i - 1048576; if (off >= 32768) return; }
  f4 a = *(const f4*)(w + off);
  f4 b = *(const f4*)(w + off + 4);
  unsigned short s[8];
  #pragma unroll
  for (int j = 0; j < 4; j++) s[j]   = (a[j] > 0.f) ? 0x3F80u : ((a[j] < 0.f) ? 0xBF80u : 0u);
  #pragma unroll
  for (int j = 0; j < 4; j++) s[4+j] = (b[j] > 0.f) ? 0x3F80u : ((b[j] < 0.f) ? 0xBF80u : 0u);
  u4 v;
  v.x = (unsigned)s[0] | ((unsigned)s[1] << 16);
  v.y = (unsigned)s[2] | ((unsigned)s[3] << 16);
  v.z = (unsigned)s[4] | ((unsigned)s[5] << 16);
  v.w = (unsigned)s[6] | ((unsigned)s[7] << 16);
  *(u4*)(o + off) = v;
}

// ---------------- GEMM1: h1(bf16) = x @ signW1^T + sign(b1), fused transposed col-stats ---------
// BM=64, BN=256, BK=64, 64 K-steps. 512 thr = 8 waves, wave tile 32x64.
// A: reg-stage fp32 (depth-4 rotating sets) -> f2bf ONCE -> b128 ds_write into bf16
//    abuf 2x8KB (XOR (m&7)<<4, conflict-free). B: GL16 depth-3 into 4x32KB bufs.
// Per step k: issue B(k+3) THEN A(k+4); COMPUTE(k); PACKA(k+1) [compiler wait ~no-op,
// A 3 steps old]; VBAR(14) drains exactly batch@k-2 -> A-slack 3 steps, B-slack 3 steps,
// ~96-144KB in flight across every barrier (Little's-law target met for the first time).
__global__ __launch_bounds__(512, 1) void gemm1_k(
    const float* __restrict__ x, const unsigned short* __restrict__ w1s,
    const float* __restrict__ b1, unsigned short* __restrict__ h1,
    float* __restrict__ part1s, float* __restrict__ part1q)
{
  __shared__ __align__(16) char lds[147456];   // A: 2x8KB @0 ; B: 4x32KB @16384
  const int tid  = threadIdx.x;
  const int lane = tid & 63;
  const int wid  = tid >> 6;
  const int wm   = wid >> 2;          // 0..1 -> rows wm*32..+31
  const int wn   = wid & 3;           // 0..3 -> cols wn*64..+63
  const int cl   = lane & 15;
  const int g    = lane >> 4;         // 0..3
  const int row0 = blockIdx.x * 64;

  // A reg-staging: thread -> row tid>>3 (0..63), 8 contiguous fp32 at (tid&7)*8
  const float* xA = x + (size_t)(row0 + (tid >> 3)) * 4096 + (tid & 7) * 8;
  const int aw = (tid >> 3) * 128 + (((tid & 7) * 16) ^ (((tid >> 3) & 7) << 4));

  // hoisted fragment read offsets
  int afo[2][2], bfo[4][2];
  #pragma unroll
  for (int fm = 0; fm < 2; fm++){
    int m = wm * 32 + fm * 16 + cl;
    #pragma unroll
    for (int ks = 0; ks < 2; ks++)
      afo[fm][ks] = m * 128 + ((ks * 64 + g * 16) ^ ((m & 7) << 4));
  }
  #pragma unroll
  for (int fn = 0; fn < 4; fn++){
    int n = wn * 64 + fn * 16 + cl;
    #pragma unroll
    for (int ks = 0; ks < 2; ks++)
      bfo[fn][ks] = n * 128 + ((ks * 64 + g * 16) ^ ((n & 7) << 4));
  }

  f4 acc[2][4];
  const f4 z = {0.f, 0.f, 0.f, 0.f};
  #pragma unroll
  for (int i = 0; i < 2; i++)
    #pragma unroll
    for (int j = 0; j < 4; j++) acc[i][j] = z;

  // 4 rotating A reg sets (2 f4 each)
  f4 rA0a, rA0b, rA1a, rA1b, rA2a, rA2b, rA3a, rA3b;

#define ISSUEA(S, K) do { \
    rA##S##a = *(const f4*)(xA + (size_t)(K) * 64); \
    rA##S##b = *(const f4*)(xA + (size_t)(K) * 64 + 4); \
  } while(0)

#define ISSUEB(BI, K) do { \
    char* _dst = lds + 16384 + (BI) * 32768; \
    _Pragma("unroll") \
    for (int _c = 0; _c < 4; _c++){ \
      int _o  = _c * 8192 + tid * 16; \
      int _n  = _o >> 7; \
      int _kb = (_o & 127) ^ ((_n & 7) << 4); \
      GL16((const char*)w1s + (size_t)_n * 8192 + (size_t)(K) * 128 + _kb, _dst + _o); \
    } } while(0)

#define PACKA(S, AB) do { \
    u4 _v; \
    _v.x = f2bf(rA##S##a[0]) | (f2bf(rA##S##a[1]) << 16); \
    _v.y = f2bf(rA##S##a[2]) | (f2bf(rA##S##a[3]) << 16); \
    _v.z = f2bf(rA##S##b[0]) | (f2bf(rA##S##b[1]) << 16); \
    _v.w = f2bf(rA##S##b[2]) | (f2bf(rA##S##b[3]) << 16); \
    *(u4*)(lds + (AB) * 8192 + aw) = _v; \
  } while(0)

#define COMPUTE(KI) do { \
    const char* _ab = lds + ((KI) & 1) * 8192; \
    const char* _bb = lds + 16384 + ((KI) & 3) * 32768; \
    short8 _af[2][2]; short8 _bf[4][2]; \
    _Pragma("unroll") \
    for (int _fm = 0; _fm < 2; _fm++) \
      _Pragma("unroll") \
      for (int _ks = 0; _ks < 2; _ks++) \
        _af[_fm][_ks] = *(const short8*)(_ab + afo[_fm][_ks]); \
    _Pragma("unroll") \
    for (int _fn = 0; _fn < 4; _fn++) \
      _Pragma("unroll") \
      for (int _ks = 0; _ks < 2; _ks++) \
        _bf[_fn][_ks] = *(const short8*)(_bb + bfo[_fn][_ks]); \
    __builtin_amdgcn_s_setprio(1); \
    _Pragma("unroll") \
    for (int _ks = 0; _ks < 2; _ks++) \
      _Pragma("unroll") \
      for (int _fm = 0; _fm < 2; _fm++) \
        _Pragma("unroll") \
        for (int _fn = 0; _fn < 4; _fn++) \
          acc[_fm][_fn] = __builtin_amdgcn_mfma_f32_16x16x32_bf16(_af[_fm][_ks], _bf[_fn][_ks], acc[_fm][_fn], 0, 0, 0); \
    __builtin_amdgcn_s_setprio(0); \
  } while(0)

// one K-step: issue B(K+3) then A(K+4) (A newest); compute K; pack A(K+1); VBAR(14)
// drains exactly batch@K-2 (B(K+1),A(K+2) remain? no: keeps {A(K+2),B(K+2),A(K+3),B(K+3),A(K+4)}=14)
#define STEP(K, AS, AP) do { \
    int _kb3 = (K) + 3; if (_kb3 > 63) _kb3 = 63; \
    int _ka4 = (K) + 4; if (_ka4 > 63) _ka4 = 63; \
    ISSUEB((K + 3) & 3, _kb3); \
    ISSUEA(AS, _ka4); \
    SB0; \
    COMPUTE(K); \
    SB0; \
    if ((K) < 63) PACKA(AP, ((K) + 1) & 1); \
    VBAR(14); \
  } while(0)

  // prologue: A(0) first (so PACKA(0) drains only it), then B(0..2), A(1..3)
  ISSUEA(0, 0);
  ISSUEB(0, 0); ISSUEB(1, 1); ISSUEB(2, 2);
  ISSUEA(1, 1); ISSUEA(2, 2); ISSUEA(3, 3);
  SB0;
  PACKA(0, 0);          // waits A(0) only (oldest)
  VBAR(14);             // drains B(0); keeps B(1),B(2),A(1..3)=14

  #pragma unroll 1
  for (int kk = 0; kk < 64; kk += 4){
    STEP(kk + 0, 0, 1);   // issue A set (k+4)&3=0, pack set (k+1)&3=1
    STEP(kk + 1, 1, 2);
    STEP(kk + 2, 2, 3);
    STEP(kk + 3, 3, 0);
  }
  asm volatile("s_waitcnt vmcnt(0)" ::: "memory");

#undef STEP
#undef COMPUTE
#undef PACKA
#undef ISSUEB
#undef ISSUEA

  // epilogue: bf16 h1 write + fused transposed column stats (per block,wm partials)
  #pragma unroll
  for (int fn = 0; fn < 4; fn++){
    int c = wn * 64 + fn * 16 + cl;
    float sb = fsign(b1[c]);
    float s = 0.f, q = 0.f;
    #pragma unroll
    for (int fm = 0; fm < 2; fm++){
      int rbase = row0 + wm * 32 + fm * 16 + g * 4;
      #pragma unroll
      for (int i = 0; i < 4; i++){
        float v = acc[fm][fn][i] + sb;
        h1[(size_t)(rbase + i) * 256 + c] = (unsigned short)f2bf(v);
        s += v; q += v * v;
      }
    }
    s += __shfl_xor(s, 16, 64); s += __shfl_xor(s, 32, 64);
    q += __shfl_xor(q, 16, 64); q += __shfl_xor(q, 32, 64);
    if (g == 0){
      part1s[(size_t)c * 512 + blockIdx.x * 2 + wm] = s;
      part1q[(size_t)c * 512 + blockIdx.x * 2 + wm] = q;
    }
  }
}

// ---------------- BN params from transposed partials ------------------------------------------
template<int COLS, int NBLK>
__global__ __launch_bounds__(64) void params_k(
    const float* __restrict__ ps, const float* __restrict__ pq,
    const float* __restrict__ g, const float* __restrict__ be,
    float* __restrict__ ab){
  int j = blockIdx.x * 64 + threadIdx.x;
  const f4* vs = (const f4*)(ps + (size_t)j * NBLK);
  const f4* vq = (const f4*)(pq + (size_t)j * NBLK);
  f4 s4 = {0,0,0,0}, q4 = {0,0,0,0};
  #pragma unroll 8
  for (int b = 0; b < NBLK/4; b++){ s4 += vs[b]; q4 += vq[b]; }
  float s = s4[0]+s4[1]+s4[2]+s4[3];
  float q = q4[0]+q4[1]+q4[2]+q4[3];
  float mu  = s * (1.f/16384.f);
  float var = q * (1.f/16384.f) - mu*mu;
  float a   = g[j] * rsqrtf(var + 1e-5f);
  ab[j] = a;
  ab[COLS + j] = be[j] - mu*a;
}

// ---------------- GEMM2: h2(bf16) = clip(BN1(h1)) @ signW2^T + sign(b2), fused stats -----------
__global__ __launch_bounds__(512) void gemm2_k(
    const unsigned short* __restrict__ h1, const unsigned short* __restrict__ w2s,
    const float* __restrict__ b2, const float* __restrict__ ab1,
    unsigned short* __restrict__ h2, float* __restrict__ part2s, float* __restrict__ part2q)
{
  __shared__ __align__(16) char lds[32768];
  __shared__ __align__(16) float a1l[256];
  __shared__ __align__(16) float c1l[256];
  const int tid  = threadIdx.x;
  const int lane = tid & 63;
  const int wid  = tid >> 6;          // 0..7 -> cols wid*16..+15
  const int cl   = lane & 15;
  const int g    = lane >> 4;
  const int klo  = g * 8;
  const int row0 = blockIdx.x * 64;

  if (tid < 256) a1l[tid] = ab1[tid];
  else           c1l[tid - 256] = ab1[tid];

  const int am  = tid >> 3;
  const int ak0 = (tid & 7) * 8;
  const unsigned short* hA = h1 + (size_t)(row0 + am) * 256 + ak0;
  const int aw = ((am * 128) + (ak0 * 2)) ^ ((am & 7) << 4);
  const unsigned short* wbase = w2s + (size_t)(wid * 16 + cl) * 256 + klo;

  u4 q0 = *(const u4*)(hA);
  u4 q1 = *(const u4*)(hA + 64);
  u4 q2 = *(const u4*)(hA + 128);
  u4 q3 = *(const u4*)(hA + 192);
  short8 Bq0, Bq1, Br0, Br1;
  Bq0 = *(const short8*)(wbase);
  Bq1 = *(const short8*)(wbase + 32);

  BARRIER();                 // a1l/c1l visible

#define TRW(KB, RAW) do { \
    f4 _a0 = *(const f4*)(&a1l[(KB)*64 + ak0]); \
    f4 _a1 = *(const f4*)(&a1l[(KB)*64 + ak0 + 4]); \
    f4 _c0 = *(const f4*)(&c1l[(KB)*64 + ak0]); \
    f4 _c1 = *(const f4*)(&c1l[(KB)*64 + ak0 + 4]); \
    float _t0 = hclip(_a0[0]*bflo(RAW.x) + _c0[0]); \
    float _t1 = hclip(_a0[1]*bfhi(RAW.x) + _c0[1]); \
    float _t2 = hclip(_a0[2]*bflo(RAW.y) + _c0[2]); \
    float _t3 = hclip(_a0[3]*bfhi(RAW.y) + _c0[3]); \
    float _t4 = hclip(_a1[0]*bflo(RAW.z) + _c1[0]); \
    float _t5 = hclip(_a1[1]*bfhi(RAW.z) + _c1[1]); \
    float _t6 = hclip(_a1[2]*bflo(RAW.w) + _c1[2]); \
    float _t7 = hclip(_a1[3]*bfhi(RAW.w) + _c1[3]); \
    u4 _v; \
    _v.x = f2bf(_t0) | (f2bf(_t1) << 16); \
    _v.y = f2bf(_t2) | (f2bf(_t3) << 16); \
    _v.z = f2bf(_t4) | (f2bf(_t5) << 16); \
    _v.w = f2bf(_t6) | (f2bf(_t7) << 16); \
    *(u4*)(lds + (KB)*8192 + aw) = _v; \
  } while(0)

  TRW(0, q0); TRW(1, q1); TRW(2, q2); TRW(3, q3);
#undef TRW
  BARRIER();

  f4 acc[4];
  const f4 z = {0.f, 0.f, 0.f, 0.f};
  #pragma unroll
  for (int i = 0; i < 4; i++) acc[i] = z;

#define LOADB2(P, KB) do { \
    B##P##0 = *(const short8*)(wbase + (KB)*64); \
    B##P##1 = *(const short8*)(wbase + (KB)*64 + 32); \
  } while(0)

#define COMP2(BASE, P) do { \
    const char* _ab = (const char*)(BASE); \
    short8 _af[4][2]; \
    _Pragma("unroll") \
    for (int fm = 0; fm < 4; fm++){ \
      int _m = fm*16 + cl; \
      _af[fm][0] = *(const short8*)(_ab + ((_m*128 + klo*2) ^ ((_m & 7) << 4))); \
      _af[fm][1] = *(const short8*)(_ab + ((_m*128 + (32 + klo)*2) ^ ((_m & 7) << 4))); \
    } \
    _Pragma("unroll") \
    for (int fm = 0; fm < 4; fm++){ \
      acc[fm] = __builtin_amdgcn_mfma_f32_16x16x32_bf16(_af[fm][0], B##P##0, acc[fm], 0, 0, 0); \
      acc[fm] = __builtin_amdgcn_mfma_f32_16x16x32_bf16(_af[fm][1], B##P##1, acc[fm], 0, 0, 0); \
    } \
  } while(0)

  LOADB2(r, 1);
  COMP2(lds,         q);
  LOADB2(q, 2);
  COMP2(lds +  8192, r);
  LOADB2(r, 3);
  COMP2(lds + 16384, q);
  COMP2(lds + 24576, r);
#undef COMP2
#undef LOADB2

  {
    int c = wid*16 + cl;
    float sb = fsign(b2[c]);
    float s = 0.f, q = 0.f;
    #pragma unroll
    for (int fm = 0; fm < 4; fm++){
      int rbase = row0 + fm*16 + g*4;
      #pragma unroll
      for (int i = 0; i < 4; i++){
        float v = acc[fm][i] + sb;
        h2[(size_t)(rbase + i)*128 + c] = (unsigned short)f2bf(v);
        s += v; q += v*v;
      }
    }
    s += __shfl_xor(s, 16, 64); s += __shfl_xor(s, 32, 64);
    q += __shfl_xor(q, 16, 64); q += __shfl_xor(q, 32, 64);
    if (g == 0){
      part2s[c*256 + blockIdx.x] = s;
      part2q[c*256 + blockIdx.x] = q;
    }
  }
}

// ---------------- final: out = clip(BN2(h2)) @ W4^T + b4, BN2 params fused ---------------------
__global__ __launch_bounds__(128) void final_k(
    const unsigned short* __restrict__ h2,
    const float* __restrict__ part2s, const float* __restrict__ part2q,
    const float* __restrict__ g2, const float* __restrict__ be2,
    const float* __restrict__ W4, const float* __restrict__ b4,
    float* __restrict__ out)
{
  __shared__ __align__(16) float W4l[12*128];
  __shared__ __align__(16) float a2l[128];
  __shared__ __align__(16) float c2l[128];
  const int t = threadIdx.x;
  #pragma unroll
  for (int i = 0; i < 3; i++)
    *(f4*)&W4l[(i*128 + t)*4] = *(const f4*)(W4 + (i*128 + t)*4);
  {
    const f4* vs = (const f4*)(part2s + t*256);
    const f4* vq = (const f4*)(part2q + t*256);
    f4 s4 = {0,0,0,0}, q4 = {0,0,0,0};
    #pragma unroll 8
    for (int b = 0; b < 64; b++){ s4 += vs[b]; q4 += vq[b]; }
    float s = s4[0]+s4[1]+s4[2]+s4[3];
    float q = q4[0]+q4[1]+q4[2]+q4[3];
    float mu  = s * (1.f/16384.f);
    float var = q * (1.f/16384.f) - mu*mu;
    float a   = g2[t] * rsqrtf(var + 1e-5f);
    a2l[t] = a;
    c2l[t] = be2[t] - mu*a;
  }
  __syncthreads();

  const int r = blockIdx.x * 128 + t;
  const u4* hp = (const u4*)(h2 + (size_t)r * 128);
  u4 hv0 = hp[0], hv1 = hp[1], hv2 = hp[2],  hv3 = hp[3];
  u4 hv4 = hp[4], hv5 = hp[5], hv6 = hp[6],  hv7 = hp[7];
  u4 hv8 = hp[8], hv9 = hp[9], hv10 = hp[10], hv11 = hp[11];
  u4 hv12 = hp[12], hv13 = hp[13], hv14 = hp[14], hv15 = hp[15];

  float acc[12];
  #pragma unroll
  for (int o = 0; o < 12; o++) acc[o] = b4[o];

#define FPROC(HV, J) do { \
    f4 a0 = *(const f4*)&a2l[(J)*8];     f4 a1 = *(const f4*)&a2l[(J)*8 + 4]; \
    f4 c0 = *(const f4*)&c2l[(J)*8];     f4 c1 = *(const f4*)&c2l[(J)*8 + 4]; \
    float tt0 = hclip(a0[0]*bflo(HV.x) + c0[0]); \
    float tt1 = hclip(a0[1]*bfhi(HV.x) + c0[1]); \
    float tt2 = hclip(a0[2]*bflo(HV.y) + c0[2]); \
    float tt3 = hclip(a0[3]*bfhi(HV.y) + c0[3]); \
    float tt4 = hclip(a1[0]*bflo(HV.z) + c1[0]); \
    float tt5 = hclip(a1[1]*bfhi(HV.z) + c1[1]); \
    float tt6 = hclip(a1[2]*bflo(HV.w) + c1[2]); \
    float tt7 = hclip(a1[3]*bfhi(HV.w) + c1[3]); \
    _Pragma("unroll") \
    for (int o = 0; o < 12; o++){ \
      f4 w0 = *(const f4*)&W4l[o*128 + (J)*8]; \
      f4 w1 = *(const f4*)&W4l[o*128 + (J)*8 + 4]; \
      acc[o] += tt0*w0[0] + tt1*w0[1] + tt2*w0[2] + tt3*w0[3] \
              + tt4*w1[0] + tt5*w1[1] + tt6*w1[2] + tt7*w1[3]; \
    } \
  } while(0)

  FPROC(hv0, 0);  FPROC(hv1, 1);  FPROC(hv2, 2);   FPROC(hv3, 3);
  FPROC(hv4, 4);  FPROC(hv5, 5);  FPROC(hv6, 6);   FPROC(hv7, 7);
  FPROC(hv8, 8);  FPROC(hv9, 9);  FPROC(hv10, 10); FPROC(hv11, 11);
  FPROC(hv12, 12); FPROC(hv13, 13); FPROC(hv14, 14); FPROC(hv15, 15);
#undef FPROC

  #pragma unroll
  for (int o = 0; o < 12; o++) out[(size_t)r*12 + o] = acc[o];
}

// ---------------- launch ----------------
extern "C" void kernel_launch(void* const* d_in, const int* in_sizes, int n_in,
                              void* d_out, int out_size, void* d_ws, size_t ws_size,
                              hipStream_t stream)
{
  const float* x   = (const float*)d_in[0];
  const float* W1  = (const float*)d_in[1];
  const float* b1  = (const float*)d_in[2];
  const float* g1  = (const float*)d_in[3];
  const float* be1 = (const float*)d_in[4];
  const float* W2  = (const float*)d_in[5];
  const float* b2  = (const float*)d_in[6];
  const float* g2  = (const float*)d_in[7];
  const float* be2 = (const float*)d_in[8];
  const float* W4  = (const float*)d_in[9];
  const float* b4  = (const float*)d_in[10];
  float* out = (float*)d_out;

  char* ws = (char*)d_ws;
  unsigned short* h1     = (unsigned short*)(ws);              //  8 MB  [16384,256] bf16
  unsigned short* h2     = (unsigned short*)(ws + 8388608);    //  4 MB  [16384,128] bf16
  unsigned short* w1s    = (unsigned short*)(ws + 12582912);   //  2 MB  [256,4096] bf16
  unsigned short* w2s    = (unsigned short*)(ws + 14680064);   // 64 KB  [128,256] bf16
  float*          part1s = (float*)(ws + 14745600);            // 512 KB [256][512]
  float*          part1q = (float*)(ws + 15269888);            // 512 KB
  float*          part2s = (float*)(ws + 15794176);            // 128 KB [128][256]
  float*          part2q = (float*)(ws + 15925248);            // 128 KB
  float*          ab1    = (float*)(ws + 16056320);            // a1[256], c1[256]

  prep_sign_k<<<528, 256, 0, stream>>>(W1, w1s, W2, w2s);
  gemm1_k<<<256, 512, 0, stream>>>(x, w1s, b1, h1, part1s, part1q);
  params_k<256, 512><<<4, 64, 0, stream>>>(part1s, part1q, g1, be1, ab1);
  gemm2_k<<<256, 512, 0, stream>>>(h1, w2s, b2, ab1, h2, part2s, part2q);
  final_k<<<128, 128, 0, stream>>>(h2, part2s, part2q, g2, be2, W4, b4, out);
}